// Round 1
// baseline (77.744 us; speedup 1.0000x reference)
//
#include <hip/hip_runtime.h>

// Persistence-image kernel, MI355X.
// S=128 samples, I=32 intervals, C=32 corners, R=30 grid -> G=900.
// img[s,g] = sum_i w_i^2 * exp(-200 * max(min_c |g-b_ic|^2, min_c |g-d_ic|^2))
// Expansion |g-p|^2 = (|p|^2 - 2 g.p) + |g|^2 -> 3 VALU/corner (fma,fma,min).

#define RES 30
#define GPTS 900
#define NS 128
#define NI 32
#define NC 32
#define INV29 (1.0f / 29.0f)

// ---------------- prep: per-sample bbox (lo/hi with margin) + w^2 ----------------
__global__ __launch_bounds__(256) void prep_kernel(
    const float* __restrict__ births, const float* __restrict__ deaths,
    float* __restrict__ ws)
{
    const int s   = blockIdx.x;
    const int tid = threadIdx.x;

    // min/max over all 2048 (x,y) points of this sample (births + deaths)
    const float4* b4 = (const float4*)(births + (size_t)s * 2048);
    const float4* d4 = (const float4*)(deaths + (size_t)s * 2048);
    float mnx = 3e38f, mny = 3e38f, mxx = -3e38f, mxy = -3e38f;
    for (int k = tid; k < 512; k += 256) {
        float4 f = b4[k];
        mnx = fminf(mnx, fminf(f.x, f.z)); mxx = fmaxf(mxx, fmaxf(f.x, f.z));
        mny = fminf(mny, fminf(f.y, f.w)); mxy = fmaxf(mxy, fmaxf(f.y, f.w));
        float4 g = d4[k];
        mnx = fminf(mnx, fminf(g.x, g.z)); mxx = fmaxf(mxx, fmaxf(g.x, g.z));
        mny = fminf(mny, fminf(g.y, g.w)); mxy = fmaxf(mxy, fmaxf(g.y, g.w));
    }
    #pragma unroll
    for (int off = 32; off > 0; off >>= 1) {
        mnx = fminf(mnx, __shfl_down(mnx, off));
        mny = fminf(mny, __shfl_down(mny, off));
        mxx = fmaxf(mxx, __shfl_down(mxx, off));
        mxy = fmaxf(mxy, __shfl_down(mxy, off));
    }
    __shared__ float red[4][4];
    const int wave = tid >> 6, lane = tid & 63;
    if (lane == 0) { red[wave][0] = mnx; red[wave][1] = mny; red[wave][2] = mxx; red[wave][3] = mxy; }
    __syncthreads();
    if (tid == 0) {
        float a = red[0][0], b = red[0][1], c = red[0][2], d = red[0][3];
        #pragma unroll
        for (int w = 1; w < 4; ++w) {
            a = fminf(a, red[w][0]); b = fminf(b, red[w][1]);
            c = fmaxf(c, red[w][2]); d = fmaxf(d, red[w][3]);
        }
        const float mgx = 0.1f * (c - a), mgy = 0.1f * (d - b);
        ws[s * 4 + 0] = a - mgx; ws[s * 4 + 1] = b - mgy;
        ws[s * 4 + 2] = c + mgx; ws[s * 4 + 3] = d + mgy;
    }

    // w2[s][i] = (mean_c max(|dx|,|dy|))^2 ; 8 threads per interval, 4 corners each
    const float2* bp = (const float2*)(births + (size_t)s * 2048);
    const float2* dp = (const float2*)(deaths + (size_t)s * 2048);
    const int i = tid >> 3, q = tid & 7;
    float part = 0.f;
    #pragma unroll
    for (int k = 0; k < 4; ++k) {
        const int c = q * 4 + k;
        float2 fb = bp[i * 32 + c], fd = dp[i * 32 + c];
        part += fmaxf(fabsf(fd.x - fb.x), fabsf(fd.y - fb.y));
    }
    part += __shfl_down(part, 4);
    part += __shfl_down(part, 2);
    part += __shfl_down(part, 1);
    if (q == 0) {
        const float w = part * (1.0f / 32.0f);
        ws[512 + s * 32 + i] = w * w;
    }
}

// ---------------- main: block = (sample, 4-interval chunk); NG=8 grid pts/thread ----------------
__global__ __launch_bounds__(128) void pimg_kernel(
    const float* __restrict__ births, const float* __restrict__ deaths,
    const float* __restrict__ ws, float* __restrict__ out)
{
    const int bid = blockIdx.x;
    const int s   = bid >> 3;
    const int i0  = (bid & 7) * 4;
    const int tid = threadIdx.x;

    __shared__ __align__(16) float Bqx[128], Bqy[128], Br[128];
    __shared__ __align__(16) float Dqx[128], Dqy[128], Dr[128];

    // transform 4 intervals x 32 corners -> (qx=-2x, qy=-2y, r=x^2+y^2) SoA
    {
        const int il = tid >> 5, c = tid & 31;
        const size_t base = (size_t)s * 1024 + (size_t)(i0 + il) * 32 + c;
        const float2 pb = ((const float2*)births)[base];
        Bqx[tid] = -2.f * pb.x; Bqy[tid] = -2.f * pb.y; Br[tid] = pb.x * pb.x + pb.y * pb.y;
        const float2 pd = ((const float2*)deaths)[base];
        Dqx[tid] = -2.f * pd.x; Dqy[tid] = -2.f * pd.y; Dr[tid] = pd.x * pd.x + pd.y * pd.y;
    }

    const float lox = ws[s * 4 + 0], loy = ws[s * 4 + 1];
    const float sx  = (ws[s * 4 + 2] - lox) * INV29;
    const float sy  = (ws[s * 4 + 3] - loy) * INV29;

    float gx[8], gy[8], gg[8], acc[8];
    #pragma unroll
    for (int j = 0; j < 8; ++j) {
        const int g  = tid + 128 * j;
        const int ix = g / RES, iy = g - ix * RES;
        gx[j]  = lox + (float)ix * sx;
        gy[j]  = loy + (float)iy * sy;
        gg[j]  = gx[j] * gx[j] + gy[j] * gy[j];
        acc[j] = 0.f;
    }
    __syncthreads();

    const float4* Bqx4 = (const float4*)Bqx;
    const float4* Bqy4 = (const float4*)Bqy;
    const float4* Br4  = (const float4*)Br;
    const float4* Dqx4 = (const float4*)Dqx;
    const float4* Dqy4 = (const float4*)Dqy;
    const float4* Dr4  = (const float4*)Dr;

    #pragma unroll 1
    for (int il = 0; il < 4; ++il) {
        float mb[8], md[8];
        #pragma unroll
        for (int j = 0; j < 8; ++j) { mb[j] = 3e38f; md[j] = 3e38f; }

        #pragma unroll
        for (int q = 0; q < 8; ++q) {
            const float4 X = Bqx4[il * 8 + q];
            const float4 Y = Bqy4[il * 8 + q];
            const float4 Rr = Br4[il * 8 + q];
            const float xs[4] = {X.x, X.y, X.z, X.w};
            const float ys[4] = {Y.x, Y.y, Y.z, Y.w};
            const float rs[4] = {Rr.x, Rr.y, Rr.z, Rr.w};
            #pragma unroll
            for (int c = 0; c < 4; ++c) {
                #pragma unroll
                for (int j = 0; j < 8; ++j) {
                    float a = fmaf(xs[c], gx[j], rs[c]);
                    a = fmaf(ys[c], gy[j], a);
                    mb[j] = fminf(mb[j], a);
                }
            }
        }
        #pragma unroll
        for (int q = 0; q < 8; ++q) {
            const float4 X = Dqx4[il * 8 + q];
            const float4 Y = Dqy4[il * 8 + q];
            const float4 Rr = Dr4[il * 8 + q];
            const float xs[4] = {X.x, X.y, X.z, X.w};
            const float ys[4] = {Y.x, Y.y, Y.z, Y.w};
            const float rs[4] = {Rr.x, Rr.y, Rr.z, Rr.w};
            #pragma unroll
            for (int c = 0; c < 4; ++c) {
                #pragma unroll
                for (int j = 0; j < 8; ++j) {
                    float a = fmaf(xs[c], gx[j], rs[c]);
                    a = fmaf(ys[c], gy[j], a);
                    md[j] = fminf(md[j], a);
                }
            }
        }

        const float w2 = ws[512 + s * 32 + i0 + il];
        #pragma unroll
        for (int j = 0; j < 8; ++j) {
            const float t = fmaxf(mb[j], md[j]) + gg[j];
            acc[j] = fmaf(w2, __expf(-200.0f * t), acc[j]);
        }
    }

    #pragma unroll
    for (int j = 0; j < 8; ++j) {
        const int g = tid + 128 * j;
        if (g < GPTS) atomicAdd(&out[(size_t)s * GPTS + g], acc[j]);
    }
}

extern "C" void kernel_launch(void* const* d_in, const int* in_sizes, int n_in,
                              void* d_out, int out_size, void* d_ws, size_t ws_size,
                              hipStream_t stream) {
    const float* births = (const float*)d_in[0];
    const float* deaths = (const float*)d_in[1];
    float* out = (float*)d_out;
    float* ws  = (float*)d_ws;

    hipMemsetAsync(out, 0, (size_t)out_size * sizeof(float), stream);
    prep_kernel<<<NS, 256, 0, stream>>>(births, deaths, ws);
    pimg_kernel<<<NS * 8, 128, 0, stream>>>(births, deaths, ws, out);
}

// Round 2
// 77.679 us; speedup vs baseline: 1.0008x; 1.0008x over previous
//
#include <hip/hip_runtime.h>

// Persistence-image kernel, MI355X — fully fused single kernel.
// S=128 samples, I=32 intervals, C=32 corners, R=30 grid -> G=900.
// img[s,g] = sum_i w_i^2 * exp(-200 * max(min_c |g-b_ic|^2, min_c |g-d_ic|^2))
// |g-p|^2 = (|p|^2 - 2 g.p) + |g|^2 -> inner op = fma,fma,min (3 VALU/corner).
// Each block: (sample s, 4-interval chunk). Redundant per-block bbox/w2 prep
// (~16KB L2-resident reads + ~200 VALU) replaces a separate low-occupancy
// prep kernel + its serialized dispatch.

#define RES 30
#define GPTS 900
#define NS 128
#define INV29 (1.0f / 29.0f)

__global__ __launch_bounds__(128) void pimg_kernel(
    const float* __restrict__ births, const float* __restrict__ deaths,
    float* __restrict__ out)
{
    const int bid = blockIdx.x;
    const int s   = bid >> 3;
    const int i0  = (bid & 7) * 4;
    const int tid = threadIdx.x;

    __shared__ __align__(16) float Bqx[128], Bqy[128], Br[128];
    __shared__ __align__(16) float Dqx[128], Dqy[128], Dr[128];
    __shared__ float wred[128];
    __shared__ float red[2][4];
    __shared__ float box[4];
    __shared__ float w2s[4];

    // ---- corner transform for this block's 4 intervals: (qx=-2x, qy=-2y, r=|p|^2)
    {
        const int il = tid >> 5, c = tid & 31;
        const size_t base = (size_t)s * 1024 + (size_t)(i0 + il) * 32 + c;
        const float2 pb = ((const float2*)births)[base];
        Bqx[tid] = -2.f * pb.x; Bqy[tid] = -2.f * pb.y; Br[tid] = pb.x * pb.x + pb.y * pb.y;
        const float2 pd = ((const float2*)deaths)[base];
        Dqx[tid] = -2.f * pd.x; Dqy[tid] = -2.f * pd.y; Dr[tid] = pd.x * pd.x + pd.y * pd.y;
        // interval-weight partial: per-corner max(|dx|,|dy|)
        wred[tid] = fmaxf(fabsf(pd.x - pb.x), fabsf(pd.y - pb.y));
    }

    // ---- redundant per-block bbox over all 2048 points of sample s
    {
        const float4* b4 = (const float4*)(births + (size_t)s * 2048);
        const float4* d4 = (const float4*)(deaths + (size_t)s * 2048);
        float mnx = 3e38f, mny = 3e38f, mxx = -3e38f, mxy = -3e38f;
        #pragma unroll
        for (int k = 0; k < 4; ++k) {
            float4 f = b4[tid + 128 * k];
            mnx = fminf(mnx, fminf(f.x, f.z)); mxx = fmaxf(mxx, fmaxf(f.x, f.z));
            mny = fminf(mny, fminf(f.y, f.w)); mxy = fmaxf(mxy, fmaxf(f.y, f.w));
            float4 g = d4[tid + 128 * k];
            mnx = fminf(mnx, fminf(g.x, g.z)); mxx = fmaxf(mxx, fmaxf(g.x, g.z));
            mny = fminf(mny, fminf(g.y, g.w)); mxy = fmaxf(mxy, fmaxf(g.y, g.w));
        }
        #pragma unroll
        for (int off = 32; off > 0; off >>= 1) {
            mnx = fminf(mnx, __shfl_down(mnx, off));
            mny = fminf(mny, __shfl_down(mny, off));
            mxx = fmaxf(mxx, __shfl_down(mxx, off));
            mxy = fmaxf(mxy, __shfl_down(mxy, off));
        }
        const int wave = tid >> 6, lane = tid & 63;
        if (lane == 0) { red[wave][0] = mnx; red[wave][1] = mny; red[wave][2] = mxx; red[wave][3] = mxy; }
    }
    __syncthreads();

    if (tid == 0) {
        const float a = fminf(red[0][0], red[1][0]);
        const float b = fminf(red[0][1], red[1][1]);
        const float c = fmaxf(red[0][2], red[1][2]);
        const float d = fmaxf(red[0][3], red[1][3]);
        const float mgx = 0.1f * (c - a), mgy = 0.1f * (d - b);
        box[0] = a - mgx; box[1] = b - mgy; box[2] = c + mgx; box[3] = d + mgy;
    }
    if (tid < 4) {  // w2 per interval: serial sum of 32 per-corner values (deterministic)
        float ssum = 0.f;
        #pragma unroll
        for (int k = 0; k < 32; ++k) ssum += wred[tid * 32 + k];
        const float w = ssum * (1.0f / 32.0f);
        w2s[tid] = w * w;
    }
    __syncthreads();

    const float lox = box[0], loy = box[1];
    const float sx  = (box[2] - lox) * INV29;
    const float sy  = (box[3] - loy) * INV29;

    float gx[8], gy[8], gg[8], acc[8];
    #pragma unroll
    for (int j = 0; j < 8; ++j) {
        const int g  = tid + 128 * j;
        const int ix = g / RES, iy = g - ix * RES;
        gx[j]  = lox + (float)ix * sx;
        gy[j]  = loy + (float)iy * sy;
        gg[j]  = gx[j] * gx[j] + gy[j] * gy[j];
        acc[j] = 0.f;
    }

    const float4* Bqx4 = (const float4*)Bqx;
    const float4* Bqy4 = (const float4*)Bqy;
    const float4* Br4  = (const float4*)Br;
    const float4* Dqx4 = (const float4*)Dqx;
    const float4* Dqy4 = (const float4*)Dqy;
    const float4* Dr4  = (const float4*)Dr;

    #pragma unroll 1
    for (int il = 0; il < 4; ++il) {
        float mb[8], md[8];
        #pragma unroll
        for (int j = 0; j < 8; ++j) { mb[j] = 3e38f; md[j] = 3e38f; }

        #pragma unroll
        for (int q = 0; q < 8; ++q) {
            const float4 X  = Bqx4[il * 8 + q];
            const float4 Y  = Bqy4[il * 8 + q];
            const float4 Rr = Br4[il * 8 + q];
            const float xs[4] = {X.x, X.y, X.z, X.w};
            const float ys[4] = {Y.x, Y.y, Y.z, Y.w};
            const float rs[4] = {Rr.x, Rr.y, Rr.z, Rr.w};
            #pragma unroll
            for (int c = 0; c < 4; ++c) {
                #pragma unroll
                for (int j = 0; j < 8; ++j) {
                    float a = fmaf(xs[c], gx[j], rs[c]);
                    a = fmaf(ys[c], gy[j], a);
                    mb[j] = fminf(mb[j], a);
                }
            }
        }
        #pragma unroll
        for (int q = 0; q < 8; ++q) {
            const float4 X  = Dqx4[il * 8 + q];
            const float4 Y  = Dqy4[il * 8 + q];
            const float4 Rr = Dr4[il * 8 + q];
            const float xs[4] = {X.x, X.y, X.z, X.w};
            const float ys[4] = {Y.x, Y.y, Y.z, Y.w};
            const float rs[4] = {Rr.x, Rr.y, Rr.z, Rr.w};
            #pragma unroll
            for (int c = 0; c < 4; ++c) {
                #pragma unroll
                for (int j = 0; j < 8; ++j) {
                    float a = fmaf(xs[c], gx[j], rs[c]);
                    a = fmaf(ys[c], gy[j], a);
                    md[j] = fminf(md[j], a);
                }
            }
        }

        const float w2 = w2s[il];
        #pragma unroll
        for (int j = 0; j < 8; ++j) {
            const float t = fmaxf(mb[j], md[j]) + gg[j];
            acc[j] = fmaf(w2, __expf(-200.0f * t), acc[j]);
        }
    }

    #pragma unroll
    for (int j = 0; j < 8; ++j) {
        const int g = tid + 128 * j;
        if (g < GPTS) atomicAdd(&out[(size_t)s * GPTS + g], acc[j]);
    }
}

extern "C" void kernel_launch(void* const* d_in, const int* in_sizes, int n_in,
                              void* d_out, int out_size, void* d_ws, size_t ws_size,
                              hipStream_t stream) {
    const float* births = (const float*)d_in[0];
    const float* deaths = (const float*)d_in[1];
    float* out = (float*)d_out;

    hipMemsetAsync(out, 0, (size_t)out_size * sizeof(float), stream);
    pimg_kernel<<<NS * 8, 128, 0, stream>>>(births, deaths, out);
}

// Round 3
// 75.022 us; speedup vs baseline: 1.0363x; 1.0354x over previous
//
#include <hip/hip_runtime.h>

// Persistence-image kernel, MI355X — fused, occupancy-doubled.
// S=128, I=32 intervals, C=32 corners, R=30 -> G=900.
// img[s,g] = sum_i w_i^2 * exp(-200 * max(min_c |g-b_ic|^2, min_c |g-d_ic|^2))
// |g-p|^2 = (|p|^2 - 2 g.p) + |g|^2 -> inner op = fma,fma,min.
// Block = (sample, 2-interval chunk): 2048 blocks -> 8 blocks/CU, 4 waves/SIMD
// (was 2) to hide LDS-broadcast + exp latency. Bbox/w2 computed redundantly
// per block (L2-resident).

#define RES 30
#define GPTS 900
#define NS 128
#define INV29 (1.0f / 29.0f)

__global__ __launch_bounds__(128) void pimg_kernel(
    const float* __restrict__ births, const float* __restrict__ deaths,
    float* __restrict__ out)
{
    const int bid = blockIdx.x;
    const int s   = bid >> 4;
    const int i0  = (bid & 15) * 2;
    const int tid = threadIdx.x;

    __shared__ __align__(16) float Bqx[64], Bqy[64], Br[64];
    __shared__ __align__(16) float Dqx[64], Dqy[64], Dr[64];
    __shared__ float wred[64];
    __shared__ float red[2][4];
    __shared__ float box[4];
    __shared__ float w2s[2];

    // ---- corner transform for this block's 2 intervals (threads 0..63)
    if (tid < 64) {
        const size_t base = (size_t)s * 1024 + (size_t)i0 * 32 + tid;
        const float2 pb = ((const float2*)births)[base];
        Bqx[tid] = -2.f * pb.x; Bqy[tid] = -2.f * pb.y; Br[tid] = pb.x * pb.x + pb.y * pb.y;
        const float2 pd = ((const float2*)deaths)[base];
        Dqx[tid] = -2.f * pd.x; Dqy[tid] = -2.f * pd.y; Dr[tid] = pd.x * pd.x + pd.y * pd.y;
        wred[tid] = fmaxf(fabsf(pd.x - pb.x), fabsf(pd.y - pb.y));
    }

    // ---- redundant per-block bbox over all 2048 points of sample s
    {
        const float4* b4 = (const float4*)(births + (size_t)s * 2048);
        const float4* d4 = (const float4*)(deaths + (size_t)s * 2048);
        float mnx = 3e38f, mny = 3e38f, mxx = -3e38f, mxy = -3e38f;
        #pragma unroll
        for (int k = 0; k < 4; ++k) {
            float4 f = b4[tid + 128 * k];
            mnx = fminf(mnx, fminf(f.x, f.z)); mxx = fmaxf(mxx, fmaxf(f.x, f.z));
            mny = fminf(mny, fminf(f.y, f.w)); mxy = fmaxf(mxy, fmaxf(f.y, f.w));
            float4 g = d4[tid + 128 * k];
            mnx = fminf(mnx, fminf(g.x, g.z)); mxx = fmaxf(mxx, fmaxf(g.x, g.z));
            mny = fminf(mny, fminf(g.y, g.w)); mxy = fmaxf(mxy, fmaxf(g.y, g.w));
        }
        #pragma unroll
        for (int off = 32; off > 0; off >>= 1) {
            mnx = fminf(mnx, __shfl_down(mnx, off));
            mny = fminf(mny, __shfl_down(mny, off));
            mxx = fmaxf(mxx, __shfl_down(mxx, off));
            mxy = fmaxf(mxy, __shfl_down(mxy, off));
        }
        const int wave = tid >> 6, lane = tid & 63;
        if (lane == 0) { red[wave][0] = mnx; red[wave][1] = mny; red[wave][2] = mxx; red[wave][3] = mxy; }
    }
    __syncthreads();

    if (tid == 0) {
        const float a = fminf(red[0][0], red[1][0]);
        const float b = fminf(red[0][1], red[1][1]);
        const float c = fmaxf(red[0][2], red[1][2]);
        const float d = fmaxf(red[0][3], red[1][3]);
        const float mgx = 0.1f * (c - a), mgy = 0.1f * (d - b);
        box[0] = a - mgx; box[1] = b - mgy; box[2] = c + mgx; box[3] = d + mgy;
    }
    if (tid < 2) {  // deterministic serial sum of 32 per-corner weights
        float ssum = 0.f;
        #pragma unroll
        for (int k = 0; k < 32; ++k) ssum += wred[tid * 32 + k];
        const float w = ssum * (1.0f / 32.0f);
        w2s[tid] = w * w;
    }
    __syncthreads();

    const float lox = box[0], loy = box[1];
    const float sx  = (box[2] - lox) * INV29;
    const float sy  = (box[3] - loy) * INV29;

    float gx[8], gy[8], gg[8], acc[8];
    #pragma unroll
    for (int j = 0; j < 8; ++j) {
        const int g  = tid + 128 * j;
        const int ix = g / RES, iy = g - ix * RES;
        gx[j]  = lox + (float)ix * sx;
        gy[j]  = loy + (float)iy * sy;
        gg[j]  = gx[j] * gx[j] + gy[j] * gy[j];
        acc[j] = 0.f;
    }

    const float4* Bqx4 = (const float4*)Bqx;
    const float4* Bqy4 = (const float4*)Bqy;
    const float4* Br4  = (const float4*)Br;
    const float4* Dqx4 = (const float4*)Dqx;
    const float4* Dqy4 = (const float4*)Dqy;
    const float4* Dr4  = (const float4*)Dr;

    #pragma unroll 1
    for (int il = 0; il < 2; ++il) {
        float mb[8], md[8];
        #pragma unroll
        for (int j = 0; j < 8; ++j) { mb[j] = 3e38f; md[j] = 3e38f; }

        #pragma unroll
        for (int q = 0; q < 8; ++q) {
            const float4 X  = Bqx4[il * 8 + q];
            const float4 Y  = Bqy4[il * 8 + q];
            const float4 Rr = Br4[il * 8 + q];
            #pragma unroll
            for (int j = 0; j < 8; ++j) {
                float a0 = fmaf(X.x, gx[j], Rr.x); a0 = fmaf(Y.x, gy[j], a0); mb[j] = fminf(mb[j], a0);
                float a1 = fmaf(X.y, gx[j], Rr.y); a1 = fmaf(Y.y, gy[j], a1); mb[j] = fminf(mb[j], a1);
                float a2 = fmaf(X.z, gx[j], Rr.z); a2 = fmaf(Y.z, gy[j], a2); mb[j] = fminf(mb[j], a2);
                float a3 = fmaf(X.w, gx[j], Rr.w); a3 = fmaf(Y.w, gy[j], a3); mb[j] = fminf(mb[j], a3);
            }
        }
        #pragma unroll
        for (int q = 0; q < 8; ++q) {
            const float4 X  = Dqx4[il * 8 + q];
            const float4 Y  = Dqy4[il * 8 + q];
            const float4 Rr = Dr4[il * 8 + q];
            #pragma unroll
            for (int j = 0; j < 8; ++j) {
                float a0 = fmaf(X.x, gx[j], Rr.x); a0 = fmaf(Y.x, gy[j], a0); md[j] = fminf(md[j], a0);
                float a1 = fmaf(X.y, gx[j], Rr.y); a1 = fmaf(Y.y, gy[j], a1); md[j] = fminf(md[j], a1);
                float a2 = fmaf(X.z, gx[j], Rr.z); a2 = fmaf(Y.z, gy[j], a2); md[j] = fminf(md[j], a2);
                float a3 = fmaf(X.w, gx[j], Rr.w); a3 = fmaf(Y.w, gy[j], a3); md[j] = fminf(md[j], a3);
            }
        }

        const float w2 = w2s[il];
        #pragma unroll
        for (int j = 0; j < 8; ++j) {
            const float t = fmaxf(mb[j], md[j]) + gg[j];
            acc[j] = fmaf(w2, __expf(-200.0f * t), acc[j]);
        }
    }

    #pragma unroll
    for (int j = 0; j < 8; ++j) {
        const int g = tid + 128 * j;
        if (g < GPTS) atomicAdd(&out[(size_t)s * GPTS + g], acc[j]);
    }
}

extern "C" void kernel_launch(void* const* d_in, const int* in_sizes, int n_in,
                              void* d_out, int out_size, void* d_ws, size_t ws_size,
                              hipStream_t stream) {
    const float* births = (const float*)d_in[0];
    const float* deaths = (const float*)d_in[1];
    float* out = (float*)d_out;

    hipMemsetAsync(out, 0, (size_t)out_size * sizeof(float), stream);
    pimg_kernel<<<NS * 16, 128, 0, stream>>>(births, deaths, out);
}

// Round 4
// 74.531 us; speedup vs baseline: 1.0431x; 1.0066x over previous
//
#include <hip/hip_runtime.h>

// Persistence-image kernel, MI355X — fused, max-occupancy variant.
// S=128, I=32 intervals, C=32 corners, R=30 -> G=900.
// img[s,g] = sum_i w_i^2 * exp(-200 * max(min_c |g-b_ic|^2, min_c |g-d_ic|^2))
// |g-p|^2 = (|p|^2 - 2 g.p) + |g|^2 -> inner op = fma,fma,min.
// Block = (sample, 2-interval chunk, g-half): 4096 blocks -> 16 blocks/CU,
// 8 waves/SIMD (HW max), VGPR capped at 64 via __launch_bounds__(128,8).
// Bbox/w2 computed redundantly per block (L2-resident, overlapped).

#define RES 30
#define GPTS 900
#define NS 128
#define INV29 (1.0f / 29.0f)

__global__ __launch_bounds__(128, 8) void pimg_kernel(
    const float* __restrict__ births, const float* __restrict__ deaths,
    float* __restrict__ out)
{
    const int bid = blockIdx.x;
    const int s   = bid >> 5;
    const int i0  = ((bid >> 1) & 15) * 2;
    const int gh  = bid & 1;
    const int tid = threadIdx.x;

    __shared__ __align__(16) float Bqx[64], Bqy[64], Br[64];
    __shared__ __align__(16) float Dqx[64], Dqy[64], Dr[64];
    __shared__ float wred[64];
    __shared__ float red[2][4];
    __shared__ float box[4];
    __shared__ float w2s[2];

    // ---- corner transform for this block's 2 intervals (threads 0..63)
    if (tid < 64) {
        const size_t base = (size_t)s * 1024 + (size_t)i0 * 32 + tid;
        const float2 pb = ((const float2*)births)[base];
        Bqx[tid] = -2.f * pb.x; Bqy[tid] = -2.f * pb.y; Br[tid] = pb.x * pb.x + pb.y * pb.y;
        const float2 pd = ((const float2*)deaths)[base];
        Dqx[tid] = -2.f * pd.x; Dqy[tid] = -2.f * pd.y; Dr[tid] = pd.x * pd.x + pd.y * pd.y;
        wred[tid] = fmaxf(fabsf(pd.x - pb.x), fabsf(pd.y - pb.y));
    }

    // ---- redundant per-block bbox over all 2048 points of sample s
    {
        const float4* b4 = (const float4*)(births + (size_t)s * 2048);
        const float4* d4 = (const float4*)(deaths + (size_t)s * 2048);
        float mnx = 3e38f, mny = 3e38f, mxx = -3e38f, mxy = -3e38f;
        #pragma unroll
        for (int k = 0; k < 4; ++k) {
            float4 f = b4[tid + 128 * k];
            mnx = fminf(mnx, fminf(f.x, f.z)); mxx = fmaxf(mxx, fmaxf(f.x, f.z));
            mny = fminf(mny, fminf(f.y, f.w)); mxy = fmaxf(mxy, fmaxf(f.y, f.w));
            float4 g = d4[tid + 128 * k];
            mnx = fminf(mnx, fminf(g.x, g.z)); mxx = fmaxf(mxx, fmaxf(g.x, g.z));
            mny = fminf(mny, fminf(g.y, g.w)); mxy = fmaxf(mxy, fmaxf(g.y, g.w));
        }
        #pragma unroll
        for (int off = 32; off > 0; off >>= 1) {
            mnx = fminf(mnx, __shfl_down(mnx, off));
            mny = fminf(mny, __shfl_down(mny, off));
            mxx = fmaxf(mxx, __shfl_down(mxx, off));
            mxy = fmaxf(mxy, __shfl_down(mxy, off));
        }
        const int wave = tid >> 6, lane = tid & 63;
        if (lane == 0) { red[wave][0] = mnx; red[wave][1] = mny; red[wave][2] = mxx; red[wave][3] = mxy; }
    }
    __syncthreads();

    if (tid == 0) {
        const float a = fminf(red[0][0], red[1][0]);
        const float b = fminf(red[0][1], red[1][1]);
        const float c = fmaxf(red[0][2], red[1][2]);
        const float d = fmaxf(red[0][3], red[1][3]);
        const float mgx = 0.1f * (c - a), mgy = 0.1f * (d - b);
        box[0] = a - mgx; box[1] = b - mgy; box[2] = c + mgx; box[3] = d + mgy;
    }
    if (tid < 2) {  // deterministic serial sum of 32 per-corner weights
        float ssum = 0.f;
        #pragma unroll
        for (int k = 0; k < 32; ++k) ssum += wred[tid * 32 + k];
        const float w = ssum * (1.0f / 32.0f);
        w2s[tid] = w * w;
    }
    __syncthreads();

    const float lox = box[0], loy = box[1];
    const float sx  = (box[2] - lox) * INV29;
    const float sy  = (box[3] - loy) * INV29;

    // j-interleaved g assignment: g = tid + 128*(2j+gh) -> balanced halves
    float gx[4], gy[4], acc[4];
    #pragma unroll
    for (int j = 0; j < 4; ++j) {
        const int g  = tid + 128 * (2 * j + gh);
        const int ix = g / RES, iy = g - ix * RES;
        gx[j]  = lox + (float)ix * sx;
        gy[j]  = loy + (float)iy * sy;
        acc[j] = 0.f;
    }

    const float4* Bqx4 = (const float4*)Bqx;
    const float4* Bqy4 = (const float4*)Bqy;
    const float4* Br4  = (const float4*)Br;
    const float4* Dqx4 = (const float4*)Dqx;
    const float4* Dqy4 = (const float4*)Dqy;
    const float4* Dr4  = (const float4*)Dr;

    #pragma unroll 1
    for (int il = 0; il < 2; ++il) {
        float mb[4], md[4];
        #pragma unroll
        for (int j = 0; j < 4; ++j) { mb[j] = 3e38f; md[j] = 3e38f; }

        #pragma unroll
        for (int q = 0; q < 8; ++q) {
            const float4 X  = Bqx4[il * 8 + q];
            const float4 Y  = Bqy4[il * 8 + q];
            const float4 Rr = Br4[il * 8 + q];
            #pragma unroll
            for (int j = 0; j < 4; ++j) {
                float a0 = fmaf(X.x, gx[j], Rr.x); a0 = fmaf(Y.x, gy[j], a0); mb[j] = fminf(mb[j], a0);
                float a1 = fmaf(X.y, gx[j], Rr.y); a1 = fmaf(Y.y, gy[j], a1); mb[j] = fminf(mb[j], a1);
                float a2 = fmaf(X.z, gx[j], Rr.z); a2 = fmaf(Y.z, gy[j], a2); mb[j] = fminf(mb[j], a2);
                float a3 = fmaf(X.w, gx[j], Rr.w); a3 = fmaf(Y.w, gy[j], a3); mb[j] = fminf(mb[j], a3);
            }
        }
        #pragma unroll
        for (int q = 0; q < 8; ++q) {
            const float4 X  = Dqx4[il * 8 + q];
            const float4 Y  = Dqy4[il * 8 + q];
            const float4 Rr = Dr4[il * 8 + q];
            #pragma unroll
            for (int j = 0; j < 4; ++j) {
                float a0 = fmaf(X.x, gx[j], Rr.x); a0 = fmaf(Y.x, gy[j], a0); md[j] = fminf(md[j], a0);
                float a1 = fmaf(X.y, gx[j], Rr.y); a1 = fmaf(Y.y, gy[j], a1); md[j] = fminf(md[j], a1);
                float a2 = fmaf(X.z, gx[j], Rr.z); a2 = fmaf(Y.z, gy[j], a2); md[j] = fminf(md[j], a2);
                float a3 = fmaf(X.w, gx[j], Rr.w); a3 = fmaf(Y.w, gy[j], a3); md[j] = fminf(md[j], a3);
            }
        }

        const float w2 = w2s[il];
        #pragma unroll
        for (int j = 0; j < 4; ++j) {
            const float gg = gx[j] * gx[j] + gy[j] * gy[j];  // recomputed: saves 4 VGPRs
            const float t  = fmaxf(mb[j], md[j]) + gg;
            acc[j] = fmaf(w2, __expf(-200.0f * t), acc[j]);
        }
    }

    #pragma unroll
    for (int j = 0; j < 4; ++j) {
        const int g = tid + 128 * (2 * j + gh);
        if (g < GPTS) atomicAdd(&out[(size_t)s * GPTS + g], acc[j]);
    }
}

extern "C" void kernel_launch(void* const* d_in, const int* in_sizes, int n_in,
                              void* d_out, int out_size, void* d_ws, size_t ws_size,
                              hipStream_t stream) {
    const float* births = (const float*)d_in[0];
    const float* deaths = (const float*)d_in[1];
    float* out = (float*)d_out;

    hipMemsetAsync(out, 0, (size_t)out_size * sizeof(float), stream);
    pimg_kernel<<<NS * 32, 128, 0, stream>>>(births, deaths, out);
}